// Round 14
// baseline (213.957 us; speedup 1.0000x reference)
//
#include <hip/hip_runtime.h>
#include <hip/hip_bf16.h>
#include <hip/hip_cooperative_groups.h>

namespace cg = cooperative_groups;

// Problem constants (fixed by the reference)
#define CS     128
#define EDIM   256
#define NBATCH 2
#define TLEN   8192
#define NCHUNK 64
#define LEXT   1024
#define KSEL   7

typedef __attribute__((ext_vector_type(8))) short   short8;   // 8 bf16 = 4 VGPR (MFMA A/B frag)
typedef __attribute__((ext_vector_type(4))) float   floatx4;  // MFMA C/D frag

__device__ inline short bf16_of(float f) {
    __hip_bfloat16 h = __float2bfloat16(f);
    return *(short*)&h;
}
__device__ inline float f_of_bf16(short s) {
    __hip_bfloat16 h = *(__hip_bfloat16*)&s;
    return __bfloat162float(h);
}

// async global->LDS, 16B per lane; LDS dest = wave-uniform base + lane*16
__device__ inline void gl_lds16(const void* g, void* l) {
    __builtin_amdgcn_global_load_lds(
        (const __attribute__((address_space(1))) unsigned int*)g,
        (__attribute__((address_space(3))) unsigned int*)l, 16, 0, 0);
}

// ===========================================================================
// MEGA KERNEL (cooperative): phase A (prep) -> grid.sync -> phase B (scores)
// -> grid.sync -> phase C (out + inlined topk). Phase bodies are the r13
// kernels verbatim (bit-identical numerics); LDS is a 32 KB union.
// All phases are grid-stride -> correct for ANY grid size (no deadlock).
// ===========================================================================
__global__ __launch_bounds__(256) void mega_kernel(const float* __restrict__ x,
                                                   const float* __restrict__ dp,
                                                   short* __restrict__ cn_hi,
                                                   short* __restrict__ cn_lo,
                                                   short* __restrict__ xt_hi,
                                                   short* __restrict__ dp_hi,
                                                   float* __restrict__ scores,
                                                   float* __restrict__ out) {
    __shared__ __align__(16) char smem[32768];
    cg::grid_group gg = cg::this_grid();

    const int tid  = threadIdx.x;
    const int bid  = blockIdx.x;
    const int gdim = gridDim.x;
    const int w    = tid >> 6, lane = tid & 63;
    const int quad = lane >> 4, l15 = lane & 15;
    const int rr   = lane >> 2, c16 = (lane & 3) * 8;
    const int csw  = c16 ^ (((rr >> 1) & 3) * 8);     // staging bank swizzle
    const int q8   = (quad ^ ((l15 >> 1) & 3)) * 8;   // frag-read bank swizzle

    // ---------------- Phase A: norm/split rows + dp convert + x transpose ---
    // units: [0,1024) = 16-row norm groups; [1024,1032) = dp; [1032,2056) = xt tiles
    for (int u = bid; u < 2056; u += gdim) {
        if (u < 1024) {
#pragma unroll
            for (int pass = 0; pass < 4; ++pass) {
                int row = u * 16 + w * 4 + pass;
                const float4 v = ((const float4*)(x + (size_t)row * EDIM))[lane];
                float s = v.x * v.x + v.y * v.y + v.z * v.z + v.w * v.w;
#pragma unroll
                for (int off = 1; off < 64; off <<= 1) s += __shfl_xor(s, off);
                float rn = 1.0f / (sqrtf(s) + 1e-6f);
                float c[4] = {v.x * rn, v.y * rn, v.z * rn, v.w * rn};
                short hs[4], ls[4];
#pragma unroll
                for (int q = 0; q < 4; ++q) {
                    hs[q] = bf16_of(c[q]);
                    ls[q] = bf16_of(c[q] - f_of_bf16(hs[q]));
                }
                size_t o = (size_t)row * EDIM + lane * 4;
                *(short4*)(cn_hi + o) = make_short4(hs[0], hs[1], hs[2], hs[3]);
                *(short4*)(cn_lo + o) = make_short4(ls[0], ls[1], ls[2], ls[3]);
            }
        } else if (u < 1032) {
            int t = (u - 1024) * 256 + tid;
#pragma unroll
            for (int k = 0; k < 16; ++k) {
                int idx = (t * 16 + k) * 4;
                float4 v = *(const float4*)(dp + idx);
                *(short4*)(dp_hi + idx) =
                    make_short4(bf16_of(v.x), bf16_of(v.y), bf16_of(v.z), bf16_of(v.w));
            }
        } else {
            // xt transpose tile 64e x 64t, fp32 LDS tile pitch 68 (17 KB)
            float* tile = (float*)smem;
            int ut = u - 1032;
            int b2 = ut >> 9, et = (ut >> 7) & 3, tt2 = ut & 127;
            int e0 = et * 64, t0 = tt2 * 64;
            int r2 = tid >> 2, c4 = (tid & 3) * 16;
            const float* src = x + ((size_t)(b2 * TLEN + t0 + r2)) * EDIM + e0 + c4;
#pragma unroll
            for (int k = 0; k < 4; ++k)
                *(float4*)&tile[r2 * 68 + c4 + k * 4] = *(const float4*)(src + k * 4);
            __syncthreads();
            int e = tid >> 2, tq = tid & 3;
            short hs2[16];
#pragma unroll
            for (int g = 0; g < 16; ++g) hs2[g] = bf16_of(tile[(tq * 16 + g) * 68 + e]);
            short* xd = xt_hi + ((size_t)(b2 * EDIM + e0 + e)) * TLEN + t0 + tq * 16;
#pragma unroll
            for (int q4 = 0; q4 < 4; ++q4)
                *(short4*)(xd + q4 * 4) =
                    make_short4(hs2[q4*4], hs2[q4*4+1], hs2[q4*4+2], hs2[q4*4+3]);
            __syncthreads();
        }
    }
    gg.sync();

    // ---------------- Phase B: scores (r13 body; 4032 units) ----------------
    {
        short (*tiles)[4096] = (short(*)[4096])smem;   // 32 KB exactly
        double* red2  = (double*)smem;                 // alias (epilogue only)
        float*  redbuf = (float*)(smem + 16);

        for (int u = bid; u < 4032; u += gdim) {
            const int b = u & 1, p = u >> 1;
            int i = (int)((1.0f + sqrtf(1.0f + 8.0f * (float)p)) * 0.5f);
            while (i * (i - 1) / 2 > p) --i;
            while (i * (i + 1) / 2 <= p) ++i;
            const int j = p - i * (i - 1) / 2;

            const short* sarr  = (w & 1) ? cn_lo : cn_hi;
            const size_t sbase = ((size_t)b * TLEN + ((w >> 1) ? j : i) * CS) * EDIM;
            const int wr = w >> 1, wc = w & 1;

            floatx4 acc[4][4];
#pragma unroll
            for (int rt = 0; rt < 4; ++rt)
#pragma unroll
                for (int ct = 0; ct < 4; ++ct) acc[rt][ct] = (floatx4){0.f, 0.f, 0.f, 0.f};

            for (int ks = 0; ks < 8; ++ks) {
                const short* gsrc = sarr + sbase + ks * 32 + csw;
                short* ldst = &tiles[w][0];
#pragma unroll
                for (int t = 0; t < 8; ++t)
                    gl_lds16(gsrc + (size_t)(16 * t + rr) * EDIM, ldst + t * 512);
                __syncthreads();

                short8 bh[4], bl[4];
#pragma unroll
                for (int ct = 0; ct < 4; ++ct) {
                    int r = wc * 64 + ct * 16 + l15;
                    bh[ct] = *(const short8*)&tiles[2][r * 32 + q8];
                    bl[ct] = *(const short8*)&tiles[3][r * 32 + q8];
                }
#pragma unroll
                for (int rt = 0; rt < 4; ++rt) {
                    int r = wr * 64 + rt * 16 + l15;
                    short8 ah = *(const short8*)&tiles[0][r * 32 + q8];
                    short8 al = *(const short8*)&tiles[1][r * 32 + q8];
#pragma unroll
                    for (int ct = 0; ct < 4; ++ct) {
                        acc[rt][ct] = __builtin_amdgcn_mfma_f32_16x16x32_bf16(ah, bh[ct], acc[rt][ct], 0, 0, 0);
                        acc[rt][ct] = __builtin_amdgcn_mfma_f32_16x16x32_bf16(ah, bl[ct], acc[rt][ct], 0, 0, 0);
                        acc[rt][ct] = __builtin_amdgcn_mfma_f32_16x16x32_bf16(al, bh[ct], acc[rt][ct], 0, 0, 0);
                    }
                }
                __syncthreads();
            }

#pragma unroll
            for (int rt = 0; rt < 4; ++rt) {
                float m[4];
#pragma unroll
                for (int reg = 0; reg < 4; ++reg) {
                    float mm = acc[rt][0][reg];
#pragma unroll
                    for (int ct = 1; ct < 4; ++ct) mm = fmaxf(mm, acc[rt][ct][reg]);
                    m[reg] = mm;
                }
#pragma unroll
                for (int off = 1; off < 16; off <<= 1)
#pragma unroll
                    for (int reg = 0; reg < 4; ++reg) m[reg] = fmaxf(m[reg], __shfl_xor(m[reg], off));
                if (l15 == 0) {
#pragma unroll
                    for (int reg = 0; reg < 4; ++reg)
                        redbuf[wc * 128 + wr * 64 + rt * 16 + quad * 4 + reg] = m[reg];
                }
            }
            __syncthreads();

            double part = 0.0;
            if (tid < 128) part = (double)fmaxf(redbuf[tid], redbuf[128 + tid]);
#pragma unroll
            for (int off = 1; off < 64; off <<= 1) part += __shfl_xor(part, off);
            if (lane == 0 && w < 2) red2[w] = part;
            __syncthreads();
            if (tid == 0) scores[(b * NCHUNK + i) * NCHUNK + j] = (float)(red2[0] + red2[1]);
            // (no extra barrier needed: wave-0's next staging is program-ordered
            //  after tid0's red2 read; waves 1-3 stage tiles[1..3] only)
        }
    }
    gg.sync();

    // ---------------- Phase C: out + inlined topk (r13 body; 512 units) -----
    {
        short* As    = (short*)smem;             // [2][128*32] = 16 KB
        short* Bs    = (short*)(smem + 16384);   // [2][64*32]  =  8 KB
        int*   slist = (int*)(smem + 24576);
        int*   sslot = (int*)(smem + 24608);
        float* swei  = (float*)(smem + 24640);
        int*   snum  = (int*)(smem + 24672);

        for (int u = bid; u < 512; u += gdim) {
            const int eq = u & 3, n = (u >> 2) & 63, b = u >> 8;
            const int e0 = eq * 64;
            const int wr = w >> 1, wc = w & 1;

            if (w == 0) {
                const float* srow = scores + (b * NCHUNK + n) * NCHUNK;
                const int nsel = n < KSEL ? n : KSEL;
                float v = (lane < n) ? srow[lane] : -3.0e38f;
                float vals[KSEL];
                int   idxs[KSEL];
                for (int s2 = 0; s2 < nsel; ++s2) {
                    float bv = v; int bi = lane;
#pragma unroll
                    for (int off = 1; off < 64; off <<= 1) {
                        float ov = __shfl_xor(bv, off);
                        int   oi = __shfl_xor(bi, off);
                        if (ov > bv || (ov == bv && oi < bi)) { bv = ov; bi = oi; }
                    }
                    vals[s2] = bv; idxs[s2] = bi;
                    if (lane == bi) v = -3.0e38f;
                }
                if (lane == 0) {
                    float vmin = (nsel > 0) ? vals[nsel - 1] : 0.0f;
                    float inv  = 1.0f / (vmin + 1e-6f);
                    int shift  = KSEL - nsel;
                    int c = 0;
                    for (int s2 = 0; s2 < 8; ++s2) {
                        int jj; float ww;
                        if (s2 < KSEL) {
                            int tt = s2 - shift;
                            if (tt >= 0) { jj = idxs[tt]; ww = vals[tt] * inv; }
                            else         { jj = -1;       ww = 0.0f; }
                        } else { jj = n; ww = 1.0f; }
                        if (jj >= 0) { slist[c] = jj; sslot[c] = s2; swei[c] = ww; ++c; }
                    }
                    *snum = c;
                }
            }
            __syncthreads();
            const int NS = (*snum) * 4;

            auto stage = [&](int st, int bf) {
                int sv = st >> 2, kk = st & 3;
                if (w < 2) {
                    const short* gsrc = dp_hi + (size_t)(sslot[sv] * 128 + kk * 32) + csw;
#pragma unroll
                    for (int t = 0; t < 4; ++t)
                        gl_lds16(gsrc + (size_t)(w * 64 + t * 16 + rr) * LEXT,
                                 As + bf * 4096 + (w * 64 + t * 16) * 32);
                } else {
                    const short* gsrc = xt_hi + ((size_t)(b * EDIM + e0)) * TLEN
                                        + (size_t)(slist[sv] * CS + kk * 32) + csw;
#pragma unroll
                    for (int t = 0; t < 2; ++t)
                        gl_lds16(gsrc + (size_t)((w - 2) * 32 + t * 16 + rr) * TLEN,
                                 Bs + bf * 2048 + ((w - 2) * 32 + t * 16) * 32);
                }
            };

            floatx4 accT[4][2], accP[4][2];
#pragma unroll
            for (int rt = 0; rt < 4; ++rt)
#pragma unroll
                for (int ct = 0; ct < 2; ++ct) accT[rt][ct] = (floatx4){0.f, 0.f, 0.f, 0.f};

            stage(0, 0);
            __syncthreads();

            int buf = 0;
            for (int st = 0; st < NS; ++st) {
                if (st + 1 < NS) stage(st + 1, buf ^ 1);

                if ((st & 3) == 0) {
#pragma unroll
                    for (int rt = 0; rt < 4; ++rt)
#pragma unroll
                        for (int ct = 0; ct < 2; ++ct) accP[rt][ct] = (floatx4){0.f, 0.f, 0.f, 0.f};
                }

                short8 bh[2];
#pragma unroll
                for (int ct = 0; ct < 2; ++ct) {
                    int e = wc * 32 + ct * 16 + l15;
                    bh[ct] = *(const short8*)&Bs[buf * 2048 + e * 32 + q8];
                }
#pragma unroll
                for (int rt = 0; rt < 4; ++rt) {
                    int r = wr * 64 + rt * 16 + l15;
                    short8 ah = *(const short8*)&As[buf * 4096 + r * 32 + q8];
#pragma unroll
                    for (int ct = 0; ct < 2; ++ct)
                        accP[rt][ct] = __builtin_amdgcn_mfma_f32_16x16x32_bf16(ah, bh[ct], accP[rt][ct], 0, 0, 0);
                }

                if ((st & 3) == 3) {
                    float wcur = swei[st >> 2];
#pragma unroll
                    for (int rt = 0; rt < 4; ++rt)
#pragma unroll
                        for (int ct = 0; ct < 2; ++ct)
#pragma unroll
                            for (int reg = 0; reg < 4; ++reg)
                                accT[rt][ct][reg] += wcur * accP[rt][ct][reg];
                }
                __syncthreads();
                buf ^= 1;
            }

#pragma unroll
            for (int rt = 0; rt < 4; ++rt)
#pragma unroll
                for (int ct = 0; ct < 2; ++ct) {
#pragma unroll
                    for (int reg = 0; reg < 4; ++reg) {
                        int row = wr * 64 + rt * 16 + quad * 4 + reg;
                        int col = wc * 32 + ct * 16 + l15;
                        size_t o = ((size_t)(b * TLEN + n * CS + row)) * EDIM + e0 + col;
                        out[o] = accT[rt][ct][reg] + x[o];
                    }
                }
            __syncthreads();   // meta/As/Bs reuse by next unit
        }
    }
}

// ===========================================================================
// FALLBACK PATH: r13 three-kernel pipeline (used if cooperative launch fails)
// ===========================================================================
__global__ __launch_bounds__(256) void prep_kernel(const float* __restrict__ x,
                                                   const float* __restrict__ dp,
                                                   short* __restrict__ cn_hi,
                                                   short* __restrict__ cn_lo,
                                                   short* __restrict__ xt_hi,
                                                   short* __restrict__ dp_hi) {
    const int bx = blockIdx.x;
    if (bx >= 256) {
        int t = (bx - 256) * 256 + threadIdx.x;
#pragma unroll
        for (int u = 0; u < 16; ++u) {
            int idx = (t * 16 + u) * 4;
            float4 v = *(const float4*)(dp + idx);
            *(short4*)(dp_hi + idx) =
                make_short4(bf16_of(v.x), bf16_of(v.y), bf16_of(v.z), bf16_of(v.w));
        }
        return;
    }
    __shared__ float tile[64 * 257];
    const int b = bx >> 7, t0 = (bx & 127) * 64;
    const int tid = threadIdx.x;
    const int r = tid >> 2, q = tid & 3;
    const float* src = x + ((size_t)(b * TLEN + t0 + r)) * EDIM + q * 64;
    float* trow = &tile[r * 257 + q * 64];
    float s = 0.f;
#pragma unroll
    for (int u = 0; u < 16; ++u) {
        float4 v = *(const float4*)(src + u * 4);
        s += v.x * v.x + v.y * v.y + v.z * v.z + v.w * v.w;
        trow[u * 4 + 0] = v.x; trow[u * 4 + 1] = v.y;
        trow[u * 4 + 2] = v.z; trow[u * 4 + 3] = v.w;
    }
    s += __shfl_xor(s, 1);
    s += __shfl_xor(s, 2);
    const float rn = 1.0f / (sqrtf(s) + 1e-6f);
    short* ch = cn_hi + ((size_t)(b * TLEN + t0 + r)) * EDIM + q * 64;
    short* cl = cn_lo + ((size_t)(b * TLEN + t0 + r)) * EDIM + q * 64;
#pragma unroll
    for (int u = 0; u < 16; ++u) {
        short hs[4], ls[4];
#pragma unroll
        for (int k2 = 0; k2 < 4; ++k2) {
            float c = trow[u * 4 + k2] * rn;
            hs[k2] = bf16_of(c);
            ls[k2] = bf16_of(c - f_of_bf16(hs[k2]));
        }
        *(short4*)(ch + u * 4) = make_short4(hs[0], hs[1], hs[2], hs[3]);
        *(short4*)(cl + u * 4) = make_short4(ls[0], ls[1], ls[2], ls[3]);
    }
    __syncthreads();
    const int g16 = tid >> 4, tq = tid & 15;
#pragma unroll
    for (int it = 0; it < 16; ++it) {
        int e = g16 + it * 16;
        short hs2[4];
#pragma unroll
        for (int g = 0; g < 4; ++g)
            hs2[g] = bf16_of(tile[(tq * 4 + g) * 257 + e]);
        *(short4*)(xt_hi + ((size_t)(b * EDIM + e)) * TLEN + t0 + tq * 4)
            = make_short4(hs2[0], hs2[1], hs2[2], hs2[3]);
    }
}

__global__ __launch_bounds__(256) void scores_mfma(const short* __restrict__ cn_hi,
                                                   const short* __restrict__ cn_lo,
                                                   float* __restrict__ scores) {
    __shared__ short tiles[4][4096];
    double* red2  = (double*)&tiles[0][0];
    float*  redbuf = (float*)&tiles[0][8];

    const int p = blockIdx.x, b = blockIdx.y;
    int i = (int)((1.0f + sqrtf(1.0f + 8.0f * (float)p)) * 0.5f);
    while (i * (i - 1) / 2 > p) --i;
    while (i * (i + 1) / 2 <= p) ++i;
    const int j = p - i * (i - 1) / 2;

    const int tid  = threadIdx.x;
    const int w    = tid >> 6, lane = tid & 63;
    const int wr   = w >> 1, wc = w & 1;
    const int quad = lane >> 4, l15 = lane & 15;
    const short* sarr  = (w & 1) ? cn_lo : cn_hi;
    const size_t sbase = ((size_t)b * TLEN + ((w >> 1) ? j : i) * CS) * EDIM;
    const int rr  = lane >> 2;
    const int c16 = (lane & 3) * 8;
    const int csw = c16 ^ (((rr >> 1) & 3) * 8);
    const int q8  = (quad ^ ((l15 >> 1) & 3)) * 8;

    floatx4 acc[4][4];
#pragma unroll
    for (int rt = 0; rt < 4; ++rt)
#pragma unroll
        for (int ct = 0; ct < 4; ++ct) acc[rt][ct] = (floatx4){0.f, 0.f, 0.f, 0.f};

    for (int ks = 0; ks < 8; ++ks) {
        const short* gsrc = sarr + sbase + ks * 32 + csw;
        short* ldst = &tiles[w][0];
#pragma unroll
        for (int t = 0; t < 8; ++t)
            gl_lds16(gsrc + (size_t)(16 * t + rr) * EDIM, ldst + t * 512);
        __syncthreads();
        short8 bh[4], bl[4];
#pragma unroll
        for (int ct = 0; ct < 4; ++ct) {
            int r = wc * 64 + ct * 16 + l15;
            bh[ct] = *(const short8*)&tiles[2][r * 32 + q8];
            bl[ct] = *(const short8*)&tiles[3][r * 32 + q8];
        }
#pragma unroll
        for (int rt = 0; rt < 4; ++rt) {
            int r = wr * 64 + rt * 16 + l15;
            short8 ah = *(const short8*)&tiles[0][r * 32 + q8];
            short8 al = *(const short8*)&tiles[1][r * 32 + q8];
#pragma unroll
            for (int ct = 0; ct < 4; ++ct) {
                acc[rt][ct] = __builtin_amdgcn_mfma_f32_16x16x32_bf16(ah, bh[ct], acc[rt][ct], 0, 0, 0);
                acc[rt][ct] = __builtin_amdgcn_mfma_f32_16x16x32_bf16(ah, bl[ct], acc[rt][ct], 0, 0, 0);
                acc[rt][ct] = __builtin_amdgcn_mfma_f32_16x16x32_bf16(al, bh[ct], acc[rt][ct], 0, 0, 0);
            }
        }
        __syncthreads();
    }
#pragma unroll
    for (int rt = 0; rt < 4; ++rt) {
        float m[4];
#pragma unroll
        for (int reg = 0; reg < 4; ++reg) {
            float mm = acc[rt][0][reg];
#pragma unroll
            for (int ct = 1; ct < 4; ++ct) mm = fmaxf(mm, acc[rt][ct][reg]);
            m[reg] = mm;
        }
#pragma unroll
        for (int off = 1; off < 16; off <<= 1)
#pragma unroll
            for (int reg = 0; reg < 4; ++reg) m[reg] = fmaxf(m[reg], __shfl_xor(m[reg], off));
        if (l15 == 0) {
#pragma unroll
            for (int reg = 0; reg < 4; ++reg)
                redbuf[wc * 128 + wr * 64 + rt * 16 + quad * 4 + reg] = m[reg];
        }
    }
    __syncthreads();
    double part = 0.0;
    if (tid < 128) part = (double)fmaxf(redbuf[tid], redbuf[128 + tid]);
#pragma unroll
    for (int off = 1; off < 64; off <<= 1) part += __shfl_xor(part, off);
    if (lane == 0 && w < 2) red2[w] = part;
    __syncthreads();
    if (tid == 0) scores[(b * NCHUNK + i) * NCHUNK + j] = (float)(red2[0] + red2[1]);
}

__global__ __launch_bounds__(256) void out_mfma(const float* __restrict__ x,
                                                const short* __restrict__ dph,
                                                const short* __restrict__ xth,
                                                const float* __restrict__ scores,
                                                float* __restrict__ out) {
    __shared__ short As[2][128 * 32];
    __shared__ short Bs[2][64 * 32];
    __shared__ int   slist[8], sslot[8], snum;
    __shared__ float swei[8];

    const int eq = blockIdx.x, n = blockIdx.y, b = blockIdx.z;
    const int e0 = eq * 64;
    const int tid  = threadIdx.x;
    const int w    = tid >> 6, lane = tid & 63;
    const int wr   = w >> 1, wc = w & 1;
    const int quad = lane >> 4, l15 = lane & 15;
    const int rr   = lane >> 2;
    const int c16  = (lane & 3) * 8;
    const int csw  = c16 ^ (((rr >> 1) & 3) * 8);
    const int q8   = (quad ^ ((l15 >> 1) & 3)) * 8;

    if (w == 0) {
        const float* srow = scores + (b * NCHUNK + n) * NCHUNK;
        const int nsel = n < KSEL ? n : KSEL;
        float v = (lane < n) ? srow[lane] : -3.0e38f;
        float vals[KSEL];
        int   idxs[KSEL];
        for (int s2 = 0; s2 < nsel; ++s2) {
            float bv = v; int bi = lane;
#pragma unroll
            for (int off = 1; off < 64; off <<= 1) {
                float ov = __shfl_xor(bv, off);
                int   oi = __shfl_xor(bi, off);
                if (ov > bv || (ov == bv && oi < bi)) { bv = ov; bi = oi; }
            }
            vals[s2] = bv; idxs[s2] = bi;
            if (lane == bi) v = -3.0e38f;
        }
        if (lane == 0) {
            float vmin = (nsel > 0) ? vals[nsel - 1] : 0.0f;
            float inv  = 1.0f / (vmin + 1e-6f);
            int shift  = KSEL - nsel;
            int c = 0;
            for (int s2 = 0; s2 < 8; ++s2) {
                int jj; float ww;
                if (s2 < KSEL) {
                    int tt = s2 - shift;
                    if (tt >= 0) { jj = idxs[tt]; ww = vals[tt] * inv; }
                    else         { jj = -1;       ww = 0.0f; }
                } else { jj = n; ww = 1.0f; }
                if (jj >= 0) { slist[c] = jj; sslot[c] = s2; swei[c] = ww; ++c; }
            }
            snum = c;
        }
    }
    __syncthreads();
    const int NS = snum * 4;

    auto stage = [&](int st, int bf) {
        int sv = st >> 2, kk = st & 3;
        if (w < 2) {
            const short* gsrc = dph + (size_t)(sslot[sv] * 128 + kk * 32) + csw;
#pragma unroll
            for (int t = 0; t < 4; ++t)
                gl_lds16(gsrc + (size_t)(w * 64 + t * 16 + rr) * LEXT,
                         &As[bf][(w * 64 + t * 16) * 32]);
        } else {
            const short* gsrc = xth + ((size_t)(b * EDIM + e0)) * TLEN
                                + (size_t)(slist[sv] * CS + kk * 32) + csw;
#pragma unroll
            for (int t = 0; t < 2; ++t)
                gl_lds16(gsrc + (size_t)((w - 2) * 32 + t * 16 + rr) * TLEN,
                         &Bs[bf][((w - 2) * 32 + t * 16) * 32]);
        }
    };

    floatx4 accT[4][2], accP[4][2];
#pragma unroll
    for (int rt = 0; rt < 4; ++rt)
#pragma unroll
        for (int ct = 0; ct < 2; ++ct) accT[rt][ct] = (floatx4){0.f, 0.f, 0.f, 0.f};

    stage(0, 0);
    __syncthreads();

    int buf = 0;
    for (int st = 0; st < NS; ++st) {
        if (st + 1 < NS) stage(st + 1, buf ^ 1);
        if ((st & 3) == 0) {
#pragma unroll
            for (int rt = 0; rt < 4; ++rt)
#pragma unroll
                for (int ct = 0; ct < 2; ++ct) accP[rt][ct] = (floatx4){0.f, 0.f, 0.f, 0.f};
        }
        short8 bh[2];
#pragma unroll
        for (int ct = 0; ct < 2; ++ct) {
            int e = wc * 32 + ct * 16 + l15;
            bh[ct] = *(const short8*)&Bs[buf][e * 32 + q8];
        }
#pragma unroll
        for (int rt = 0; rt < 4; ++rt) {
            int r = wr * 64 + rt * 16 + l15;
            short8 ah = *(const short8*)&As[buf][r * 32 + q8];
#pragma unroll
            for (int ct = 0; ct < 2; ++ct)
                accP[rt][ct] = __builtin_amdgcn_mfma_f32_16x16x32_bf16(ah, bh[ct], accP[rt][ct], 0, 0, 0);
        }
        if ((st & 3) == 3) {
            float wcur = swei[st >> 2];
#pragma unroll
            for (int rt = 0; rt < 4; ++rt)
#pragma unroll
                for (int ct = 0; ct < 2; ++ct)
#pragma unroll
                    for (int reg = 0; reg < 4; ++reg)
                        accT[rt][ct][reg] += wcur * accP[rt][ct][reg];
        }
        __syncthreads();
        buf ^= 1;
    }
#pragma unroll
    for (int rt = 0; rt < 4; ++rt)
#pragma unroll
        for (int ct = 0; ct < 2; ++ct) {
#pragma unroll
            for (int reg = 0; reg < 4; ++reg) {
                int row = wr * 64 + rt * 16 + quad * 4 + reg;
                int col = wc * 32 + ct * 16 + l15;
                size_t o = ((size_t)(b * TLEN + n * CS + row)) * EDIM + e0 + col;
                out[o] = accT[rt][ct][reg] + x[o];
            }
        }
}

// ---------------------------------------------------------------------------
extern "C" void kernel_launch(void* const* d_in, const int* in_sizes, int n_in,
                              void* d_out, int out_size, void* d_ws, size_t ws_size,
                              hipStream_t stream) {
    const float* x  = (const float*)d_in[0];   // [2, 8192, 256] fp32
    const float* dp = (const float*)d_in[1];   // [128, 1024] fp32
    float* out = (float*)d_out;

    char* ws = (char*)d_ws;
    short* cn_hi  = (short*)(ws);                       // 8 MB
    short* cn_lo  = (short*)(ws + (8u << 20));          // 8 MB
    short* xt_hi  = (short*)(ws + (16u << 20));         // 8 MB
    short* dp_hi  = (short*)(ws + (24u << 20));         // 256 KB
    float* scores = (float*)(ws + (25u << 20));         // 32 KB

    int nb = 0;
    hipError_t qe = hipOccupancyMaxActiveBlocksPerMultiprocessor(&nb, mega_kernel, 256, 0);
    if (qe == hipSuccess && nb >= 1) {
        int grid = nb * 256;                   // 256 CUs on MI355X
        if (grid > 1024) grid = 1024;
        void* args[] = {(void*)&x, (void*)&dp, (void*)&cn_hi, (void*)&cn_lo,
                        (void*)&xt_hi, (void*)&dp_hi, (void*)&scores, (void*)&out};
        hipError_t le = hipLaunchCooperativeKernel(mega_kernel, dim3(grid), dim3(256),
                                                   args, 0u, stream);
        if (le == hipSuccess) return;
        (void)hipGetLastError();               // clear error, fall through
    }

    // fallback: r13 three-kernel pipeline
    prep_kernel <<<dim3(264), 256, 0, stream>>>(x, dp, cn_hi, cn_lo, xt_hi, dp_hi);
    scores_mfma <<<dim3(NCHUNK * (NCHUNK - 1) / 2, NBATCH), 256, 0, stream>>>(cn_hi, cn_lo, scores);
    out_mfma    <<<dim3(4, NCHUNK, NBATCH), 256, 0, stream>>>(x, dp_hi, xt_hi, scores, out);
}